// Round 30
// baseline (4449.401 us; speedup 1.0000x reference)
//
#include <hip/hip_runtime.h>
#include <hip/hip_bf16.h>

typedef __hip_bfloat16 bf16;
typedef __attribute__((ext_vector_type(8))) short s16x8;
typedef __attribute__((ext_vector_type(4))) float f32x4;

#define NDRUG 60000
#define NDIS  40000
#define NN    100000
#define DIM   128
#define NHOPS 7
#define NEDGE 800000
#define NSB   98

__device__ __forceinline__ float u2f(unsigned short u) {
    union { unsigned int i; float f; } c; c.i = ((unsigned int)u) << 16; return c.f;
}
__device__ __forceinline__ ushort f2u(float f) {
    bf16 h = __float2bfloat16(f);
    return *reinterpret_cast<ushort*>(&h);
}

// ---------------- propagation ----------------

__global__ void k_init(const float* __restrict__ drug, const float* __restrict__ dis,
                       ushort* __restrict__ nf) {
    int i = blockIdx.x * 256 + threadIdx.x;
    if (i >= NN * 32) return;
    int n = i >> 5, g = (i & 31) << 2;
    const float* sp = (n < NDRUG) ? drug + (size_t)n * 128 + g
                                  : dis + (size_t)(n - NDRUG) * 128 + g;
    float4 v = *(const float4*)sp;
    ushort4 o;
    o.x = f2u(v.x); o.y = f2u(v.y); o.z = f2u(v.z); o.w = f2u(v.w);
    *(ushort4*)(nf + (size_t)n * 1024 + g) = o;
}

__global__ void k_count(const int* __restrict__ edst, int* __restrict__ cnt) {
    int e = blockIdx.x * 256 + threadIdx.x;
    if (e < NEDGE) atomicAdd(&cnt[edst[e]], 1);
}

__global__ void k_scanA(const int* __restrict__ cnt, int* __restrict__ incl,
                        int* __restrict__ btot) {
    __shared__ int part[1024];
    int b = blockIdx.x, t = threadIdx.x;
    int i = b * 1024 + t;
    part[t] = (i < NN) ? cnt[i] : 0;
    __syncthreads();
    for (int o = 1; o < 1024; o <<= 1) {
        int u = (t >= o) ? part[t - o] : 0;
        __syncthreads();
        part[t] += u;
        __syncthreads();
    }
    if (i < NN) incl[i] = part[t];
    if (t == 1023) btot[b] = part[1023];
}

__global__ void k_scanB(const int* __restrict__ btot, int* __restrict__ boff) {
    if (threadIdx.x == 0) {
        int run = 0;
        for (int b = 0; b < NSB; b++) { boff[b] = run; run += btot[b]; }
        boff[NSB] = run;
    }
}

__global__ void k_scanC(const int* __restrict__ cnt, const int* __restrict__ incl,
                        const int* __restrict__ boff, int* __restrict__ rp) {
    int i = blockIdx.x * 256 + threadIdx.x;
    if (i < NN) rp[i] = incl[i] - cnt[i] + boff[i >> 10];
    if (i == 0) rp[NN] = boff[NSB];
}

__global__ void k_copyrp(const int* __restrict__ rp, int* __restrict__ cur) {
    int i = blockIdx.x * 256 + threadIdx.x;
    if (i < NN) cur[i] = rp[i];
}

__global__ void k_scatter(const int* __restrict__ esrc, const int* __restrict__ edst,
                          const float* __restrict__ eval, int* __restrict__ cur,
                          int* __restrict__ ssrc, float* __restrict__ sval) {
    int e = blockIdx.x * 256 + threadIdx.x;
    if (e >= NEDGE) return;
    int d = edst[e];
    int pos = atomicAdd(&cur[d], 1);
    ssrc[pos] = esrc[e];
    sval[pos] = eval[e];
}

__global__ void k_hopg(ushort* __restrict__ nf, const int* __restrict__ rp,
                       const int* __restrict__ ssrc, const float* __restrict__ sval, int s) {
    int t = blockIdx.x * 256 + threadIdx.x;
    if (t >= NN * 32) return;
    int n = t >> 5, d0 = (t & 31) << 2;
    int e0 = rp[n], e1 = rp[n + 1];
    float4 a = make_float4(0.f, 0.f, 0.f, 0.f);
    for (int e = e0; e < e1; e++) {
        int src = ssrc[e];
        float val = sval[e];
        ushort4 u = *(const ushort4*)(nf + (size_t)src * 1024 + (size_t)(s - 1) * 128 + d0);
        a.x += u2f(u.x) * val; a.y += u2f(u.y) * val;
        a.z += u2f(u.z) * val; a.w += u2f(u.w) * val;
    }
    ushort4 o;
    o.x = f2u(a.x); o.y = f2u(a.y); o.z = f2u(a.z); o.w = f2u(a.w);
    *(ushort4*)(nf + (size_t)n * 1024 + (size_t)s * 128 + d0) = o;
}

// ---------------- weight pre-pack ----------------

__global__ void k_pack(const float* __restrict__ W, ushort* __restrict__ P, int K, int Nout) {
    int idx = blockIdx.x * 256 + threadIdx.x;
    int tot = (Nout >> 4) * (K >> 3) * 16;
    if (idx >= tot) return;
    int c = idx & 15;
    int r = idx >> 4;
    int kb = r % (K >> 3);
    int nt = r / (K >> 3);
    ushort o[8];
    #pragma unroll
    for (int i = 0; i < 8; i++)
        o[i] = f2u(W[(size_t)(kb * 8 + i) * Nout + nt * 16 + c]);
    uint4 v;
    v.x = (uint)o[0] | ((uint)o[1] << 16);
    v.y = (uint)o[2] | ((uint)o[3] << 16);
    v.z = (uint)o[4] | ((uint)o[5] << 16);
    v.w = (uint)o[6] | ((uint)o[7] << 16);
    *(uint4*)(P + (size_t)idx * 8) = v;
}

__global__ void k_catb(const float* __restrict__ qb, const float* __restrict__ kb,
                       const float* __restrict__ vb, float* __restrict__ o) {
    int i = threadIdx.x;   // 384
    o[i] = (i < 128) ? qb[i] : ((i < 256) ? kb[i - 128] : vb[i - 256]);
}

// ---------------- MFMA bf16 GEMM, full-width blocks (R18-verified) ----------------

template <int ACT, int ADD, int OUTBF, int NTPW>
__global__ void k_mgemm(const ushort* __restrict__ X, const ushort* __restrict__ Wp,
                        const float* __restrict__ bias, void* __restrict__ Yv,
                        int M, int K, int Nout) {
    int w = threadIdx.x >> 6, lane = threadIdx.x & 63;
    int lr = lane & 15, lg = lane >> 4;
    int m0 = blockIdx.x * 16;
    int kb8 = K >> 3;
    int row = m0 + lr; if (row > M - 1) row = M - 1;
    const ushort* ap = X + (size_t)row * K + lg * 8;
    f32x4 acc[NTPW] = {};
    for (int k0 = 0; k0 < K; k0 += 32, ap += 32) {
        s16x8 af = *(const s16x8*)ap;
        int kb = (k0 >> 3) + lg;
        #pragma unroll
        for (int t = 0; t < NTPW; t++) {
            int nt = w + t * 4;
            const ushort* bp = Wp + (((size_t)nt * kb8 + kb) * 16 + lr) * 8;
            s16x8 bf_ = *(const s16x8*)bp;
            acc[t] = __builtin_amdgcn_mfma_f32_16x16x32_bf16(af, bf_, acc[t], 0, 0, 0);
        }
    }
    #pragma unroll
    for (int t = 0; t < NTPW; t++) {
        int n = (w + t * 4) * 16 + lr;
        float bv = bias[n];
        #pragma unroll
        for (int j = 0; j < 4; j++) {
            int m = m0 + lg * 4 + j;
            if (m >= M) continue;
            float v = acc[t][j] + bv;
            if (ACT == 1) {
                float x = v;
                float z = 0.7978845608028654f * (x + 0.044715f * x * x * x);
                v = x / (1.0f + __expf(-2.0f * z));
            }
            if (OUTBF) {
                ((ushort*)Yv)[(size_t)m * Nout + n] = f2u(v);
            } else if (ADD) {
                ((float*)Yv)[(size_t)m * Nout + n] += v;
            } else {
                ((float*)Yv)[(size_t)m * Nout + n] = v;
            }
        }
    }
}

// ---------------- fused FULL LAYER, 32 rows (4 nodes)/block ----------------
// Each B-fragment loaded ONCE is applied to TWO row-frags (acc[2][t], R13-verified
// rf pattern) -> halves L2 weight traffic per row. Softmax/PV: wave w -> node w
// (R23-verified form, now 4 nodes). Per-element math bit-identical to R29.

__global__ void k_layer(float* __restrict__ H,
                        const ushort* __restrict__ Wqkv, const ushort* __restrict__ Wo,
                        const ushort* __restrict__ Wf1, const ushort* __restrict__ Wf2,
                        const float* __restrict__ s1v, const float* __restrict__ b1v,
                        const float* __restrict__ bqkv, const float* __restrict__ bo,
                        const float* __restrict__ s2v, const float* __restrict__ b2v,
                        const float* __restrict__ bf1, const float* __restrict__ bf2,
                        int M) {
    __shared__ float  h[32][132];
    __shared__ ushort ylds[32][136];
    __shared__ ushort big[32][520];
    __shared__ float  as_[4][256];
    int tid = threadIdx.x;
    int w = tid >> 6, lane = tid & 63;
    int lr = lane & 15, lg = lane >> 4;
    int m0 = blockIdx.x * 32;

    // load H tile -> h
    #pragma unroll
    for (int i = 0; i < 4; i++) {
        int gi = i * 256 + tid;
        int row = gi >> 5, c4 = (gi & 31) << 2;
        int grow = m0 + row; if (grow > M - 1) grow = M - 1;
        *(float4*)&h[row][c4] = *(const float4*)(H + (size_t)grow * 128 + c4);
    }
    __syncthreads();

    // LN1: wave w -> rows w*8 .. w*8+7
    #pragma unroll
    for (int i = 0; i < 8; i++) {
        int row = w * 8 + i;
        float2 x = *(const float2*)&h[row][lane * 2];
        float sum = x.x + x.y, sq = x.x * x.x + x.y * x.y;
        #pragma unroll
        for (int o = 32; o; o >>= 1) { sum += __shfl_xor(sum, o); sq += __shfl_xor(sq, o); }
        float mean = sum * (1.f / 128.f);
        float inv = rsqrtf(sq * (1.f / 128.f) - mean * mean + 1e-5f);
        float y0 = (x.x - mean) * inv * s1v[lane * 2 + 0] + b1v[lane * 2 + 0];
        float y1 = (x.y - mean) * inv * s1v[lane * 2 + 1] + b1v[lane * 2 + 1];
        *(uint*)&ylds[row][lane * 2] = (uint)f2u(y0) | ((uint)f2u(y1) << 16);
    }
    __syncthreads();

    // QKV GEMM: 2 row-frags share each B-frag
    {
        f32x4 acc[2][6] = {};
        for (int k0 = 0; k0 < 128; k0 += 32) {
            s16x8 af0 = *(const s16x8*)&ylds[lr][lg * 8 + k0];
            s16x8 af1 = *(const s16x8*)&ylds[16 + lr][lg * 8 + k0];
            int kb = (k0 >> 3) + lg;
            #pragma unroll
            for (int t = 0; t < 6; t++) {
                int nt = w + t * 4;
                const ushort* bp = Wqkv + (((size_t)nt * 16 + kb) * 16 + lr) * 8;
                s16x8 bf_ = *(const s16x8*)bp;
                acc[0][t] = __builtin_amdgcn_mfma_f32_16x16x32_bf16(af0, bf_, acc[0][t], 0, 0, 0);
                acc[1][t] = __builtin_amdgcn_mfma_f32_16x16x32_bf16(af1, bf_, acc[1][t], 0, 0, 0);
            }
        }
        #pragma unroll
        for (int t = 0; t < 6; t++) {
            int n = (w + t * 4) * 16 + lr;
            float bv = bqkv[n];
            #pragma unroll
            for (int rf = 0; rf < 2; rf++)
                #pragma unroll
                for (int j = 0; j < 4; j++)
                    big[rf * 16 + lg * 4 + j][n] = f2u(acc[rf][t][j] + bv);
        }
    }
    __syncthreads();

    // softmax: wave w -> node w (4 nodes)
    {
        int hh = lane >> 4, s_ = (lane >> 1) & 7, p = lane & 1;
        const float scale = 0.17677669529663687f;
        float dots[4];
        float mx = -1e30f;
        #pragma unroll
        for (int t4 = 0; t4 < 4; t4++) {
            int t = p * 4 + t4;
            float dot = 0.f;
            #pragma unroll
            for (int d = 0; d < 32; d++)
                dot += u2f(big[w * 8 + s_][hh * 32 + d]) * u2f(big[w * 8 + t][128 + hh * 32 + d]);
            dots[t4] = dot * scale;
            mx = fmaxf(mx, dots[t4]);
        }
        mx = fmaxf(mx, __shfl_xor(mx, 1));
        float sum = 0.f, e4[4];
        #pragma unroll
        for (int t4 = 0; t4 < 4; t4++) { e4[t4] = __expf(dots[t4] - mx); sum += e4[t4]; }
        sum += __shfl_xor(sum, 1);
        float rinv = 1.f / sum;
        #pragma unroll
        for (int t4 = 0; t4 < 4; t4++) as_[w][hh * 64 + s_ * 8 + p * 4 + t4] = e4[t4] * rinv;
    }
    __syncthreads();

    // PV: wave w -> node w (16 iters, R23-verified form)
    {
        #pragma unroll
        for (int i = 0; i < 16; i++) {
            int o = i * 64 + lane;
            int ss = o >> 7, rem = o & 127, h2 = rem >> 5, dd = rem & 31;
            float accv = 0.f;
            #pragma unroll
            for (int t = 0; t < 8; t++)
                accv += as_[w][h2 * 64 + ss * 8 + t] * u2f(big[w * 8 + t][256 + h2 * 32 + dd]);
            ylds[w * 8 + ss][rem] = f2u(accv);
        }
    }
    __syncthreads();

    // o-proj: 2 row-frags share B
    {
        f32x4 acc[2][2] = {};
        for (int k0 = 0; k0 < 128; k0 += 32) {
            s16x8 af0 = *(const s16x8*)&ylds[lr][lg * 8 + k0];
            s16x8 af1 = *(const s16x8*)&ylds[16 + lr][lg * 8 + k0];
            int kb = (k0 >> 3) + lg;
            #pragma unroll
            for (int t = 0; t < 2; t++) {
                int nt = w + t * 4;
                const ushort* bp = Wo + (((size_t)nt * 16 + kb) * 16 + lr) * 8;
                s16x8 bf_ = *(const s16x8*)bp;
                acc[0][t] = __builtin_amdgcn_mfma_f32_16x16x32_bf16(af0, bf_, acc[0][t], 0, 0, 0);
                acc[1][t] = __builtin_amdgcn_mfma_f32_16x16x32_bf16(af1, bf_, acc[1][t], 0, 0, 0);
            }
        }
        #pragma unroll
        for (int t = 0; t < 2; t++) {
            int n = (w + t * 4) * 16 + lr;
            float bv = bo[n];
            #pragma unroll
            for (int rf = 0; rf < 2; rf++)
                #pragma unroll
                for (int j = 0; j < 4; j++)
                    h[rf * 16 + lg * 4 + j][n] += acc[rf][t][j] + bv;
        }
    }
    __syncthreads();

    // LN2: wave w -> rows w*8 .. w*8+7
    #pragma unroll
    for (int i = 0; i < 8; i++) {
        int row = w * 8 + i;
        float2 x = *(const float2*)&h[row][lane * 2];
        float sum = x.x + x.y, sq = x.x * x.x + x.y * x.y;
        #pragma unroll
        for (int o = 32; o; o >>= 1) { sum += __shfl_xor(sum, o); sq += __shfl_xor(sq, o); }
        float mean = sum * (1.f / 128.f);
        float inv = rsqrtf(sq * (1.f / 128.f) - mean * mean + 1e-5f);
        float y0 = (x.x - mean) * inv * s2v[lane * 2 + 0] + b2v[lane * 2 + 0];
        float y1 = (x.y - mean) * inv * s2v[lane * 2 + 1] + b2v[lane * 2 + 1];
        *(uint*)&ylds[row][lane * 2] = (uint)f2u(y0) | ((uint)f2u(y1) << 16);
    }
    __syncthreads();

    // f1 + gelu: two 4-tile passes (VGPR cap); 2 row-frags share B
    #pragma unroll
    for (int ps = 0; ps < 2; ps++) {
        f32x4 acc[2][4] = {};
        for (int k0 = 0; k0 < 128; k0 += 32) {
            s16x8 af0 = *(const s16x8*)&ylds[lr][lg * 8 + k0];
            s16x8 af1 = *(const s16x8*)&ylds[16 + lr][lg * 8 + k0];
            int kb = (k0 >> 3) + lg;
            #pragma unroll
            for (int t = 0; t < 4; t++) {
                int nt = w + (ps * 4 + t) * 4;
                const ushort* bp = Wf1 + (((size_t)nt * 16 + kb) * 16 + lr) * 8;
                s16x8 bf_ = *(const s16x8*)bp;
                acc[0][t] = __builtin_amdgcn_mfma_f32_16x16x32_bf16(af0, bf_, acc[0][t], 0, 0, 0);
                acc[1][t] = __builtin_amdgcn_mfma_f32_16x16x32_bf16(af1, bf_, acc[1][t], 0, 0, 0);
            }
        }
        #pragma unroll
        for (int t = 0; t < 4; t++) {
            int n = (w + (ps * 4 + t) * 4) * 16 + lr;
            float bv = bf1[n];
            #pragma unroll
            for (int rf = 0; rf < 2; rf++)
                #pragma unroll
                for (int j = 0; j < 4; j++) {
                    float x = acc[rf][t][j] + bv;
                    float z = 0.7978845608028654f * (x + 0.044715f * x * x * x);
                    big[rf * 16 + lg * 4 + j][n] = f2u(x / (1.0f + __expf(-2.0f * z)));
                }
        }
    }
    __syncthreads();

    // f2 (K=512): 2 row-frags share B
    {
        f32x4 acc[2][2] = {};
        for (int k0 = 0; k0 < 512; k0 += 32) {
            s16x8 af0 = *(const s16x8*)&big[lr][lg * 8 + k0];
            s16x8 af1 = *(const s16x8*)&big[16 + lr][lg * 8 + k0];
            int kb = (k0 >> 3) + lg;
            #pragma unroll
            for (int t = 0; t < 2; t++) {
                int nt = w + t * 4;
                const ushort* bp = Wf2 + (((size_t)nt * 64 + kb) * 16 + lr) * 8;
                s16x8 bf_ = *(const s16x8*)bp;
                acc[0][t] = __builtin_amdgcn_mfma_f32_16x16x32_bf16(af0, bf_, acc[0][t], 0, 0, 0);
                acc[1][t] = __builtin_amdgcn_mfma_f32_16x16x32_bf16(af1, bf_, acc[1][t], 0, 0, 0);
            }
        }
        #pragma unroll
        for (int t = 0; t < 2; t++) {
            int n = (w + t * 4) * 16 + lr;
            float bv = bf2[n];
            #pragma unroll
            for (int rf = 0; rf < 2; rf++)
                #pragma unroll
                for (int j = 0; j < 4; j++)
                    h[rf * 16 + lg * 4 + j][n] += acc[rf][t][j] + bv;
        }
    }
    __syncthreads();

    // store h -> H
    #pragma unroll
    for (int i = 0; i < 4; i++) {
        int gi = i * 256 + tid;
        int row = gi >> 5, c4 = (gi & 31) << 2;
        int grow = m0 + row;
        if (grow < M) *(float4*)(H + (size_t)grow * 128 + c4) = *(const float4*)&h[row][c4];
    }
}

// ---------------- final LN + hop-attention pooling ----------------

__global__ void k_pool(const float* __restrict__ Hc, const float* __restrict__ fs,
                       const float* __restrict__ fb, const float* __restrict__ aw,
                       const float* __restrict__ ab, float* __restrict__ out,
                       int Nc, int n0g) {
    int w = threadIdx.x >> 6, lane = threadIdx.x & 63;
    int nl = blockIdx.x * 4 + w;
    if (nl >= Nc) return;
    const float* hp = Hc + (size_t)nl * 1024;
    float s0 = fs[lane * 2], s1 = fs[lane * 2 + 1];
    float b0 = fb[lane * 2], b1 = fb[lane * 2 + 1];
    float2 yl[8];
    #pragma unroll
    for (int s = 0; s < 8; s++) {
        float2 x = *(const float2*)(hp + s * DIM + lane * 2);
        float sum = x.x + x.y, sq = x.x * x.x + x.y * x.y;
        #pragma unroll
        for (int o = 32; o; o >>= 1) { sum += __shfl_xor(sum, o); sq += __shfl_xor(sq, o); }
        float mean = sum * (1.f / 128.f);
        float inv = rsqrtf(sq * (1.f / 128.f) - mean * mean + 1e-5f);
        yl[s].x = (x.x - mean) * inv * s0 + b0;
        yl[s].y = (x.y - mean) * inv * s1 + b1;
    }
    float awn0 = aw[lane * 2], awn1 = aw[lane * 2 + 1];
    float awh0 = aw[128 + lane * 2], awh1 = aw[128 + lane * 2 + 1];
    float abv = ab[0];
    float lg[7];
    #pragma unroll
    for (int s = 0; s < 7; s++) {
        float part = yl[0].x * awn0 + yl[0].y * awn1 + yl[s + 1].x * awh0 + yl[s + 1].y * awh1;
        #pragma unroll
        for (int o = 32; o; o >>= 1) part += __shfl_xor(part, o);
        lg[s] = part + abv;
    }
    float mx = lg[0];
    #pragma unroll
    for (int s = 1; s < 7; s++) mx = fmaxf(mx, lg[s]);
    float sum = 0.f;
    #pragma unroll
    for (int s = 0; s < 7; s++) { lg[s] = __expf(lg[s] - mx); sum += lg[s]; }
    float rinv = 1.f / sum;
    float2 f = yl[0];
    #pragma unroll
    for (int s = 0; s < 7; s++) { f.x += lg[s] * rinv * yl[s + 1].x; f.y += lg[s] * rinv * yl[s + 1].y; }
    size_t ob = (size_t)(n0g + nl) * DIM + lane * 2;
    out[ob + 0] = f.x;
    out[ob + 1] = f.y;
}

// ---------------- host ----------------

extern "C" void kernel_launch(void* const* d_in, const int* in_sizes, int n_in,
                              void* d_out, int out_size, void* d_ws, size_t ws_size,
                              hipStream_t stream) {
    const float* drug  = (const float*)d_in[4];
    const float* dis   = (const float*)d_in[5];
    const int*   esrc  = (const int*)d_in[6];
    const int*   edst  = (const int*)d_in[7];
    const float* eval  = (const float*)d_in[8];
    const float* att_w = (const float*)d_in[9];
    const float* att_b = (const float*)d_in[10];
    const float* ln1_s = (const float*)d_in[11];
    const float* ln1_b = (const float*)d_in[12];
    const float* q_w   = (const float*)d_in[13];
    const float* q_b   = (const float*)d_in[14];
    const float* k_w   = (const float*)d_in[15];
    const float* k_b   = (const float*)d_in[16];
    const float* v_w   = (const float*)d_in[17];
    const float* v_b   = (const float*)d_in[18];
    const float* o_w   = (const float*)d_in[19];
    const float* o_b   = (const float*)d_in[20];
    const float* ln2_s = (const float*)d_in[21];
    const float* ln2_b = (const float*)d_in[22];
    const float* f1_w  = (const float*)d_in[23];
    const float* f1_b  = (const float*)d_in[24];
    const float* f2_w  = (const float*)d_in[25];
    const float* f2_b  = (const float*)d_in[26];
    const float* fln_s = (const float*)d_in[27];
    const float* fln_b = (const float*)d_in[28];
    const float* aw    = (const float*)d_in[29];
    const float* ab    = (const float*)d_in[30];
    float* out = (float*)d_out;

    char* ws = (char*)d_ws;
    size_t nfB = (size_t)NN * 1024 * 2;
    ushort* nf = (ushort*)ws;
    size_t off = (nfB + 255) & ~(size_t)255;

    ushort* wpk = (ushort*)(ws + off);
    size_t offCsr = off + (1 << 20);
    int*   rp   = (int*)(ws + offCsr);
    int*   cnt  = rp + (NN + 1);
    int*   ssrc = cnt + NN;
    float* sval = (float*)(ssrc + NEDGE);
    int*   incl = (int*)(sval + NEDGE);
    int*   btot = incl + NN;
    int*   boff = btot + 128;
    size_t csrInts = (size_t)(NN + 1) + NN + NEDGE + NEDGE + NN + 256;
    size_t off2 = offCsr + ((csrInts * 4 + 255) & ~(size_t)255);

    size_t scratchB = (ws_size > off2) ? ws_size - off2 : 0;
    long long ncMax = (long long)(scratchB / 4096);
    ncMax &= ~3LL;
    if (ncMax < 4) ncMax = 4;
    int Nc = (int)((ncMax < NN) ? ncMax : NN);
    int nchunks = (NN + Nc - 1) / Nc;
    Nc = (NN + nchunks - 1) / nchunks;
    Nc = (Nc + 3) & ~3;                     // multiple of 4 -> Mc multiple of 32
    float* hbuf = (float*)(ws + off2);

    size_t wpAtt = 0;
    size_t wpQKV[2], wpO[2], wpF1[2], wpF2[2];
    {
        size_t p = 16384;
        for (int l = 0; l < 2; l++) {
            wpQKV[l] = p; p += 49152;
            wpO[l]   = p; p += 16384;
            wpF1[l]  = p; p += 65536;
            wpF2[l]  = p; p += 65536;
        }
    }
    float* qkvB = (float*)(wpk + 409600);

    // ---- pack weights ----
    {
        int b128 = (16384 / 8 + 255) / 256;
        int b512 = (65536 / 8 + 255) / 256;
        k_pack<<<b128, 256, 0, stream>>>(att_w, wpk + wpAtt, 128, 128);
        for (int l = 0; l < 2; l++) {
            k_pack<<<b128, 256, 0, stream>>>(q_w + (size_t)l * 16384, wpk + wpQKV[l], 128, 128);
            k_pack<<<b128, 256, 0, stream>>>(k_w + (size_t)l * 16384, wpk + wpQKV[l] + 16384, 128, 128);
            k_pack<<<b128, 256, 0, stream>>>(v_w + (size_t)l * 16384, wpk + wpQKV[l] + 32768, 128, 128);
            k_pack<<<b128, 256, 0, stream>>>(o_w + (size_t)l * 16384, wpk + wpO[l], 128, 128);
            k_pack<<<b512, 256, 0, stream>>>(f1_w + (size_t)l * 65536, wpk + wpF1[l], 128, 512);
            k_pack<<<b512, 256, 0, stream>>>(f2_w + (size_t)l * 65536, wpk + wpF2[l], 512, 128);
            k_catb<<<1, 384, 0, stream>>>(q_b + l * 128, k_b + l * 128, v_b + l * 128, qkvB + l * 384);
        }
    }

    // ---- CSR build ----
    (void)hipMemsetAsync(cnt, 0, (size_t)NN * 4, stream);
    k_count<<<(NEDGE + 255) / 256, 256, 0, stream>>>(edst, cnt);
    k_scanA<<<NSB, 1024, 0, stream>>>(cnt, incl, btot);
    k_scanB<<<1, 64, 0, stream>>>(btot, boff);
    k_scanC<<<(NN + 255) / 256, 256, 0, stream>>>(cnt, incl, boff, rp);
    k_copyrp<<<(NN + 255) / 256, 256, 0, stream>>>(rp, cnt);
    k_scatter<<<(NEDGE + 255) / 256, 256, 0, stream>>>(esrc, edst, eval, cnt, ssrc, sval);

    // ---- propagation ----
    k_init<<<(NN * 32 + 255) / 256, 256, 0, stream>>>(drug, dis, nf);
    for (int s = 1; s <= NHOPS; s++)
        k_hopg<<<(NN * 32 + 255) / 256, 256, 0, stream>>>(nf, rp, ssrc, sval, s);

    // ---- per-node transformer + pooling, chunked; per-LAYER dispatch (L2-hot) ----
    for (int c = 0; c < nchunks; c++) {
        int cn0 = c * Nc;
        int cn = NN - cn0; if (cn > Nc) cn = Nc;
        if (cn <= 0) break;
        int Mc = cn * 8;
        int mb16 = (Mc + 15) / 16;
        int mb32 = (Mc + 31) / 32;
        int nb = (cn + 3) / 4;

        k_mgemm<0, 0, 0, 2><<<mb16, 256, 0, stream>>>(nf + (size_t)cn0 * 1024, wpk + wpAtt,
                                                      att_b, hbuf, Mc, 128, 128);
        for (int l = 0; l < 2; l++) {
            k_layer<<<mb32, 256, 0, stream>>>(hbuf, wpk + wpQKV[l], wpk + wpO[l],
                                              wpk + wpF1[l], wpk + wpF2[l],
                                              ln1_s + l * 128, ln1_b + l * 128,
                                              qkvB + l * 384, o_b + l * 128,
                                              ln2_s + l * 128, ln2_b + l * 128,
                                              f1_b + l * 512, f2_b + l * 128, Mc);
        }
        k_pool<<<nb, 256, 0, stream>>>(hbuf, fln_s, fln_b, aw, ab, out, cn, cn0);
    }
    (void)in_sizes; (void)n_in; (void)out_size;
}

// Round 31
// 2915.112 us; speedup vs baseline: 1.5263x; 1.5263x over previous
//
#include <hip/hip_runtime.h>
#include <hip/hip_bf16.h>

typedef __hip_bfloat16 bf16;
typedef __attribute__((ext_vector_type(8))) short s16x8;
typedef __attribute__((ext_vector_type(4))) float f32x4;

#define NDRUG 60000
#define NDIS  40000
#define NN    100000
#define DIM   128
#define NHOPS 7
#define NEDGE 800000
#define NSB   98

__device__ __forceinline__ float u2f(unsigned short u) {
    union { unsigned int i; float f; } c; c.i = ((unsigned int)u) << 16; return c.f;
}
__device__ __forceinline__ ushort f2u(float f) {
    bf16 h = __float2bfloat16(f);
    return *reinterpret_cast<ushort*>(&h);
}

// ---------------- propagation ----------------

__global__ void k_init(const float* __restrict__ drug, const float* __restrict__ dis,
                       ushort* __restrict__ nf) {
    int i = blockIdx.x * 256 + threadIdx.x;
    if (i >= NN * 32) return;
    int n = i >> 5, g = (i & 31) << 2;
    const float* sp = (n < NDRUG) ? drug + (size_t)n * 128 + g
                                  : dis + (size_t)(n - NDRUG) * 128 + g;
    float4 v = *(const float4*)sp;
    ushort4 o;
    o.x = f2u(v.x); o.y = f2u(v.y); o.z = f2u(v.z); o.w = f2u(v.w);
    *(ushort4*)(nf + (size_t)n * 1024 + g) = o;
}

__global__ void k_count(const int* __restrict__ edst, int* __restrict__ cnt) {
    int e = blockIdx.x * 256 + threadIdx.x;
    if (e < NEDGE) atomicAdd(&cnt[edst[e]], 1);
}

__global__ void k_scanA(const int* __restrict__ cnt, int* __restrict__ incl,
                        int* __restrict__ btot) {
    __shared__ int part[1024];
    int b = blockIdx.x, t = threadIdx.x;
    int i = b * 1024 + t;
    part[t] = (i < NN) ? cnt[i] : 0;
    __syncthreads();
    for (int o = 1; o < 1024; o <<= 1) {
        int u = (t >= o) ? part[t - o] : 0;
        __syncthreads();
        part[t] += u;
        __syncthreads();
    }
    if (i < NN) incl[i] = part[t];
    if (t == 1023) btot[b] = part[1023];
}

__global__ void k_scanB(const int* __restrict__ btot, int* __restrict__ boff) {
    if (threadIdx.x == 0) {
        int run = 0;
        for (int b = 0; b < NSB; b++) { boff[b] = run; run += btot[b]; }
        boff[NSB] = run;
    }
}

__global__ void k_scanC(const int* __restrict__ cnt, const int* __restrict__ incl,
                        const int* __restrict__ boff, int* __restrict__ rp) {
    int i = blockIdx.x * 256 + threadIdx.x;
    if (i < NN) rp[i] = incl[i] - cnt[i] + boff[i >> 10];
    if (i == 0) rp[NN] = boff[NSB];
}

__global__ void k_copyrp(const int* __restrict__ rp, int* __restrict__ cur) {
    int i = blockIdx.x * 256 + threadIdx.x;
    if (i < NN) cur[i] = rp[i];
}

__global__ void k_scatter(const int* __restrict__ esrc, const int* __restrict__ edst,
                          const float* __restrict__ eval, int* __restrict__ cur,
                          int* __restrict__ ssrc, float* __restrict__ sval) {
    int e = blockIdx.x * 256 + threadIdx.x;
    if (e >= NEDGE) return;
    int d = edst[e];
    int pos = atomicAdd(&cur[d], 1);
    ssrc[pos] = esrc[e];
    sval[pos] = eval[e];
}

__global__ void k_hopg(ushort* __restrict__ nf, const int* __restrict__ rp,
                       const int* __restrict__ ssrc, const float* __restrict__ sval, int s) {
    int t = blockIdx.x * 256 + threadIdx.x;
    if (t >= NN * 32) return;
    int n = t >> 5, d0 = (t & 31) << 2;
    int e0 = rp[n], e1 = rp[n + 1];
    float4 a = make_float4(0.f, 0.f, 0.f, 0.f);
    for (int e = e0; e < e1; e++) {
        int src = ssrc[e];
        float val = sval[e];
        ushort4 u = *(const ushort4*)(nf + (size_t)src * 1024 + (size_t)(s - 1) * 128 + d0);
        a.x += u2f(u.x) * val; a.y += u2f(u.y) * val;
        a.z += u2f(u.z) * val; a.w += u2f(u.w) * val;
    }
    ushort4 o;
    o.x = f2u(a.x); o.y = f2u(a.y); o.z = f2u(a.z); o.w = f2u(a.w);
    *(ushort4*)(nf + (size_t)n * 1024 + (size_t)s * 128 + d0) = o;
}

// ---------------- weight pre-pack ----------------

__global__ void k_pack(const float* __restrict__ W, ushort* __restrict__ P, int K, int Nout) {
    int idx = blockIdx.x * 256 + threadIdx.x;
    int tot = (Nout >> 4) * (K >> 3) * 16;
    if (idx >= tot) return;
    int c = idx & 15;
    int r = idx >> 4;
    int kb = r % (K >> 3);
    int nt = r / (K >> 3);
    ushort o[8];
    #pragma unroll
    for (int i = 0; i < 8; i++)
        o[i] = f2u(W[(size_t)(kb * 8 + i) * Nout + nt * 16 + c]);
    uint4 v;
    v.x = (uint)o[0] | ((uint)o[1] << 16);
    v.y = (uint)o[2] | ((uint)o[3] << 16);
    v.z = (uint)o[4] | ((uint)o[5] << 16);
    v.w = (uint)o[6] | ((uint)o[7] << 16);
    *(uint4*)(P + (size_t)idx * 8) = v;
}

__global__ void k_catb(const float* __restrict__ qb, const float* __restrict__ kb,
                       const float* __restrict__ vb, float* __restrict__ o) {
    int i = threadIdx.x;   // 384
    o[i] = (i < 128) ? qb[i] : ((i < 256) ? kb[i - 128] : vb[i - 256]);
}

// ---------------- MFMA bf16 GEMM, full-width blocks (R18-verified) ----------------

template <int ACT, int ADD, int OUTBF, int NTPW>
__global__ void k_mgemm(const ushort* __restrict__ X, const ushort* __restrict__ Wp,
                        const float* __restrict__ bias, void* __restrict__ Yv,
                        int M, int K, int Nout) {
    int w = threadIdx.x >> 6, lane = threadIdx.x & 63;
    int lr = lane & 15, lg = lane >> 4;
    int m0 = blockIdx.x * 16;
    int kb8 = K >> 3;
    int row = m0 + lr; if (row > M - 1) row = M - 1;
    const ushort* ap = X + (size_t)row * K + lg * 8;
    f32x4 acc[NTPW] = {};
    for (int k0 = 0; k0 < K; k0 += 32, ap += 32) {
        s16x8 af = *(const s16x8*)ap;
        int kb = (k0 >> 3) + lg;
        #pragma unroll
        for (int t = 0; t < NTPW; t++) {
            int nt = w + t * 4;
            const ushort* bp = Wp + (((size_t)nt * kb8 + kb) * 16 + lr) * 8;
            s16x8 bf_ = *(const s16x8*)bp;
            acc[t] = __builtin_amdgcn_mfma_f32_16x16x32_bf16(af, bf_, acc[t], 0, 0, 0);
        }
    }
    #pragma unroll
    for (int t = 0; t < NTPW; t++) {
        int n = (w + t * 4) * 16 + lr;
        float bv = bias[n];
        #pragma unroll
        for (int j = 0; j < 4; j++) {
            int m = m0 + lg * 4 + j;
            if (m >= M) continue;
            float v = acc[t][j] + bv;
            if (ACT == 1) {
                float x = v;
                float z = 0.7978845608028654f * (x + 0.044715f * x * x * x);
                v = x / (1.0f + __expf(-2.0f * z));
            }
            if (OUTBF) {
                ((ushort*)Yv)[(size_t)m * Nout + n] = f2u(v);
            } else if (ADD) {
                ((float*)Yv)[(size_t)m * Nout + n] += v;
            } else {
                ((float*)Yv)[(size_t)m * Nout + n] = v;
            }
        }
    }
}

// ---------------- fused FULL LAYER (R29-banked) ----------------
// 2 nodes (16 rows)/block; per-LAYER dispatch (L2-hot weight set);
// PV on all 4 waves (R28-verified bit-identical).

__global__ void k_layer(float* __restrict__ H,
                        const ushort* __restrict__ Wqkv, const ushort* __restrict__ Wo,
                        const ushort* __restrict__ Wf1, const ushort* __restrict__ Wf2,
                        const float* __restrict__ s1v, const float* __restrict__ b1v,
                        const float* __restrict__ bqkv, const float* __restrict__ bo,
                        const float* __restrict__ s2v, const float* __restrict__ b2v,
                        const float* __restrict__ bf1, const float* __restrict__ bf2,
                        int M) {
    __shared__ float  h[16][132];
    __shared__ ushort ylds[16][136];
    __shared__ ushort big[16][520];
    __shared__ float  as_[2][256];
    int tid = threadIdx.x;
    int w = tid >> 6, lane = tid & 63;
    int lr = lane & 15, lg = lane >> 4;
    int m0 = blockIdx.x * 16;

    // load H tile -> h
    #pragma unroll
    for (int i = 0; i < 2; i++) {
        int gi = i * 256 + tid;
        int row = gi >> 5, c4 = (gi & 31) << 2;
        int grow = m0 + row; if (grow > M - 1) grow = M - 1;
        *(float4*)&h[row][c4] = *(const float4*)(H + (size_t)grow * 128 + c4);
    }
    __syncthreads();

    // LN1 (h -> ylds)
    #pragma unroll
    for (int i = 0; i < 4; i++) {
        int row = w * 4 + i;
        float2 x = *(const float2*)&h[row][lane * 2];
        float sum = x.x + x.y, sq = x.x * x.x + x.y * x.y;
        #pragma unroll
        for (int o = 32; o; o >>= 1) { sum += __shfl_xor(sum, o); sq += __shfl_xor(sq, o); }
        float mean = sum * (1.f / 128.f);
        float inv = rsqrtf(sq * (1.f / 128.f) - mean * mean + 1e-5f);
        float y0 = (x.x - mean) * inv * s1v[lane * 2 + 0] + b1v[lane * 2 + 0];
        float y1 = (x.y - mean) * inv * s1v[lane * 2 + 1] + b1v[lane * 2 + 1];
        *(uint*)&ylds[row][lane * 2] = (uint)f2u(y0) | ((uint)f2u(y1) << 16);
    }
    __syncthreads();

    // QKV GEMM (A from ylds) -> big
    {
        f32x4 acc[6] = {};
        for (int k0 = 0; k0 < 128; k0 += 32) {
            s16x8 af = *(const s16x8*)&ylds[lr][lg * 8 + k0];
            int kb = (k0 >> 3) + lg;
            #pragma unroll
            for (int t = 0; t < 6; t++) {
                int nt = w + t * 4;
                const ushort* bp = Wqkv + (((size_t)nt * 16 + kb) * 16 + lr) * 8;
                s16x8 bf_ = *(const s16x8*)bp;
                acc[t] = __builtin_amdgcn_mfma_f32_16x16x32_bf16(af, bf_, acc[t], 0, 0, 0);
            }
        }
        #pragma unroll
        for (int t = 0; t < 6; t++) {
            int n = (w + t * 4) * 16 + lr;
            float bv = bqkv[n];
            #pragma unroll
            for (int j = 0; j < 4; j++) big[lg * 4 + j][n] = f2u(acc[t][j] + bv);
        }
    }
    __syncthreads();

    // softmax (wave w<2 -> node w)
    if (w < 2) {
        int hh = lane >> 4, s_ = (lane >> 1) & 7, p = lane & 1;
        const float scale = 0.17677669529663687f;
        float dots[4];
        float mx = -1e30f;
        #pragma unroll
        for (int t4 = 0; t4 < 4; t4++) {
            int t = p * 4 + t4;
            float dot = 0.f;
            #pragma unroll
            for (int d = 0; d < 32; d++)
                dot += u2f(big[w * 8 + s_][hh * 32 + d]) * u2f(big[w * 8 + t][128 + hh * 32 + d]);
            dots[t4] = dot * scale;
            mx = fmaxf(mx, dots[t4]);
        }
        mx = fmaxf(mx, __shfl_xor(mx, 1));
        float sum = 0.f, e4[4];
        #pragma unroll
        for (int t4 = 0; t4 < 4; t4++) { e4[t4] = __expf(dots[t4] - mx); sum += e4[t4]; }
        sum += __shfl_xor(sum, 1);
        float rinv = 1.f / sum;
        #pragma unroll
        for (int t4 = 0; t4 < 4; t4++) as_[w][hh * 64 + s_ * 8 + p * 4 + t4] = e4[t4] * rinv;
    }
    __syncthreads();

    // PV on ALL 4 waves: wave w -> node w&1, half w>>1
    {
        int nd = w & 1, hf = w >> 1;
        #pragma unroll
        for (int i = 0; i < 8; i++) {
            int o = hf * 512 + i * 64 + lane;
            int ss = o >> 7, rem = o & 127, h2 = rem >> 5, dd = rem & 31;
            float accv = 0.f;
            #pragma unroll
            for (int t = 0; t < 8; t++)
                accv += as_[nd][h2 * 64 + ss * 8 + t] * u2f(big[nd * 8 + t][256 + h2 * 32 + dd]);
            ylds[nd * 8 + ss][rem] = f2u(accv);
        }
    }
    __syncthreads();

    // o-proj (A from ylds) += h
    {
        f32x4 acc[2] = {};
        for (int k0 = 0; k0 < 128; k0 += 32) {
            s16x8 af = *(const s16x8*)&ylds[lr][lg * 8 + k0];
            int kb = (k0 >> 3) + lg;
            #pragma unroll
            for (int t = 0; t < 2; t++) {
                int nt = w + t * 4;
                const ushort* bp = Wo + (((size_t)nt * 16 + kb) * 16 + lr) * 8;
                s16x8 bf_ = *(const s16x8*)bp;
                acc[t] = __builtin_amdgcn_mfma_f32_16x16x32_bf16(af, bf_, acc[t], 0, 0, 0);
            }
        }
        #pragma unroll
        for (int t = 0; t < 2; t++) {
            int n = (w + t * 4) * 16 + lr;
            float bv = bo[n];
            #pragma unroll
            for (int j = 0; j < 4; j++) h[lg * 4 + j][n] += acc[t][j] + bv;
        }
    }
    __syncthreads();

    // LN2 (h -> ylds)
    #pragma unroll
    for (int i = 0; i < 4; i++) {
        int row = w * 4 + i;
        float2 x = *(const float2*)&h[row][lane * 2];
        float sum = x.x + x.y, sq = x.x * x.x + x.y * x.y;
        #pragma unroll
        for (int o = 32; o; o >>= 1) { sum += __shfl_xor(sum, o); sq += __shfl_xor(sq, o); }
        float mean = sum * (1.f / 128.f);
        float inv = rsqrtf(sq * (1.f / 128.f) - mean * mean + 1e-5f);
        float y0 = (x.x - mean) * inv * s2v[lane * 2 + 0] + b2v[lane * 2 + 0];
        float y1 = (x.y - mean) * inv * s2v[lane * 2 + 1] + b2v[lane * 2 + 1];
        *(uint*)&ylds[row][lane * 2] = (uint)f2u(y0) | ((uint)f2u(y1) << 16);
    }
    __syncthreads();

    // f1 + gelu -> big
    {
        f32x4 acc[8] = {};
        for (int k0 = 0; k0 < 128; k0 += 32) {
            s16x8 af = *(const s16x8*)&ylds[lr][lg * 8 + k0];
            int kb = (k0 >> 3) + lg;
            #pragma unroll
            for (int t = 0; t < 8; t++) {
                int nt = w + t * 4;
                const ushort* bp = Wf1 + (((size_t)nt * 16 + kb) * 16 + lr) * 8;
                s16x8 bf_ = *(const s16x8*)bp;
                acc[t] = __builtin_amdgcn_mfma_f32_16x16x32_bf16(af, bf_, acc[t], 0, 0, 0);
            }
        }
        #pragma unroll
        for (int t = 0; t < 8; t++) {
            int n = (w + t * 4) * 16 + lr;
            float bv = bf1[n];
            #pragma unroll
            for (int j = 0; j < 4; j++) {
                float x = acc[t][j] + bv;
                float z = 0.7978845608028654f * (x + 0.044715f * x * x * x);
                big[lg * 4 + j][n] = f2u(x / (1.0f + __expf(-2.0f * z)));
            }
        }
    }
    __syncthreads();

    // f2 (K=512, A from big) += h
    {
        f32x4 acc[2] = {};
        for (int k0 = 0; k0 < 512; k0 += 32) {
            s16x8 af = *(const s16x8*)&big[lr][lg * 8 + k0];
            int kb = (k0 >> 3) + lg;
            #pragma unroll
            for (int t = 0; t < 2; t++) {
                int nt = w + t * 4;
                const ushort* bp = Wf2 + (((size_t)nt * 64 + kb) * 16 + lr) * 8;
                s16x8 bf_ = *(const s16x8*)bp;
                acc[t] = __builtin_amdgcn_mfma_f32_16x16x32_bf16(af, bf_, acc[t], 0, 0, 0);
            }
        }
        #pragma unroll
        for (int t = 0; t < 2; t++) {
            int n = (w + t * 4) * 16 + lr;
            float bv = bf2[n];
            #pragma unroll
            for (int j = 0; j < 4; j++) h[lg * 4 + j][n] += acc[t][j] + bv;
        }
    }
    __syncthreads();

    // store h -> H
    #pragma unroll
    for (int i = 0; i < 2; i++) {
        int gi = i * 256 + tid;
        int row = gi >> 5, c4 = (gi & 31) << 2;
        int grow = m0 + row;
        if (grow < M) *(float4*)(H + (size_t)grow * 128 + c4) = *(const float4*)&h[row][c4];
    }
}

// ---------------- final LN + hop-attention pooling ----------------

__global__ void k_pool(const float* __restrict__ Hc, const float* __restrict__ fs,
                       const float* __restrict__ fb, const float* __restrict__ aw,
                       const float* __restrict__ ab, float* __restrict__ out,
                       int Nc, int n0g) {
    int w = threadIdx.x >> 6, lane = threadIdx.x & 63;
    int nl = blockIdx.x * 4 + w;
    if (nl >= Nc) return;
    const float* hp = Hc + (size_t)nl * 1024;
    float s0 = fs[lane * 2], s1 = fs[lane * 2 + 1];
    float b0 = fb[lane * 2], b1 = fb[lane * 2 + 1];
    float2 yl[8];
    #pragma unroll
    for (int s = 0; s < 8; s++) {
        float2 x = *(const float2*)(hp + s * DIM + lane * 2);
        float sum = x.x + x.y, sq = x.x * x.x + x.y * x.y;
        #pragma unroll
        for (int o = 32; o; o >>= 1) { sum += __shfl_xor(sum, o); sq += __shfl_xor(sq, o); }
        float mean = sum * (1.f / 128.f);
        float inv = rsqrtf(sq * (1.f / 128.f) - mean * mean + 1e-5f);
        yl[s].x = (x.x - mean) * inv * s0 + b0;
        yl[s].y = (x.y - mean) * inv * s1 + b1;
    }
    float awn0 = aw[lane * 2], awn1 = aw[lane * 2 + 1];
    float awh0 = aw[128 + lane * 2], awh1 = aw[128 + lane * 2 + 1];
    float abv = ab[0];
    float lg[7];
    #pragma unroll
    for (int s = 0; s < 7; s++) {
        float part = yl[0].x * awn0 + yl[0].y * awn1 + yl[s + 1].x * awh0 + yl[s + 1].y * awh1;
        #pragma unroll
        for (int o = 32; o; o >>= 1) part += __shfl_xor(part, o);
        lg[s] = part + abv;
    }
    float mx = lg[0];
    #pragma unroll
    for (int s = 1; s < 7; s++) mx = fmaxf(mx, lg[s]);
    float sum = 0.f;
    #pragma unroll
    for (int s = 0; s < 7; s++) { lg[s] = __expf(lg[s] - mx); sum += lg[s]; }
    float rinv = 1.f / sum;
    float2 f = yl[0];
    #pragma unroll
    for (int s = 0; s < 7; s++) { f.x += lg[s] * rinv * yl[s + 1].x; f.y += lg[s] * rinv * yl[s + 1].y; }
    size_t ob = (size_t)(n0g + nl) * DIM + lane * 2;
    out[ob + 0] = f.x;
    out[ob + 1] = f.y;
}

// ---------------- host ----------------

extern "C" void kernel_launch(void* const* d_in, const int* in_sizes, int n_in,
                              void* d_out, int out_size, void* d_ws, size_t ws_size,
                              hipStream_t stream) {
    const float* drug  = (const float*)d_in[4];
    const float* dis   = (const float*)d_in[5];
    const int*   esrc  = (const int*)d_in[6];
    const int*   edst  = (const int*)d_in[7];
    const float* eval  = (const float*)d_in[8];
    const float* att_w = (const float*)d_in[9];
    const float* att_b = (const float*)d_in[10];
    const float* ln1_s = (const float*)d_in[11];
    const float* ln1_b = (const float*)d_in[12];
    const float* q_w   = (const float*)d_in[13];
    const float* q_b   = (const float*)d_in[14];
    const float* k_w   = (const float*)d_in[15];
    const float* k_b   = (const float*)d_in[16];
    const float* v_w   = (const float*)d_in[17];
    const float* v_b   = (const float*)d_in[18];
    const float* o_w   = (const float*)d_in[19];
    const float* o_b   = (const float*)d_in[20];
    const float* ln2_s = (const float*)d_in[21];
    const float* ln2_b = (const float*)d_in[22];
    const float* f1_w  = (const float*)d_in[23];
    const float* f1_b  = (const float*)d_in[24];
    const float* f2_w  = (const float*)d_in[25];
    const float* f2_b  = (const float*)d_in[26];
    const float* fln_s = (const float*)d_in[27];
    const float* fln_b = (const float*)d_in[28];
    const float* aw    = (const float*)d_in[29];
    const float* ab    = (const float*)d_in[30];
    float* out = (float*)d_out;

    char* ws = (char*)d_ws;
    size_t nfB = (size_t)NN * 1024 * 2;
    ushort* nf = (ushort*)ws;
    size_t off = (nfB + 255) & ~(size_t)255;

    ushort* wpk = (ushort*)(ws + off);
    size_t offCsr = off + (1 << 20);
    int*   rp   = (int*)(ws + offCsr);
    int*   cnt  = rp + (NN + 1);
    int*   ssrc = cnt + NN;
    float* sval = (float*)(ssrc + NEDGE);
    int*   incl = (int*)(sval + NEDGE);
    int*   btot = incl + NN;
    int*   boff = btot + 128;
    size_t csrInts = (size_t)(NN + 1) + NN + NEDGE + NEDGE + NN + 256;
    size_t off2 = offCsr + ((csrInts * 4 + 255) & ~(size_t)255);

    size_t scratchB = (ws_size > off2) ? ws_size - off2 : 0;
    long long ncMax = (long long)(scratchB / 4096);
    ncMax &= ~1LL;
    if (ncMax < 2) ncMax = 2;
    int Nc = (int)((ncMax < NN) ? ncMax : NN);
    int nchunks = (NN + Nc - 1) / Nc;
    Nc = (NN + nchunks - 1) / nchunks;
    if (Nc & 1) Nc++;
    float* hbuf = (float*)(ws + off2);

    size_t wpAtt = 0;
    size_t wpQKV[2], wpO[2], wpF1[2], wpF2[2];
    {
        size_t p = 16384;
        for (int l = 0; l < 2; l++) {
            wpQKV[l] = p; p += 49152;
            wpO[l]   = p; p += 16384;
            wpF1[l]  = p; p += 65536;
            wpF2[l]  = p; p += 65536;
        }
    }
    float* qkvB = (float*)(wpk + 409600);

    // ---- pack weights ----
    {
        int b128 = (16384 / 8 + 255) / 256;
        int b512 = (65536 / 8 + 255) / 256;
        k_pack<<<b128, 256, 0, stream>>>(att_w, wpk + wpAtt, 128, 128);
        for (int l = 0; l < 2; l++) {
            k_pack<<<b128, 256, 0, stream>>>(q_w + (size_t)l * 16384, wpk + wpQKV[l], 128, 128);
            k_pack<<<b128, 256, 0, stream>>>(k_w + (size_t)l * 16384, wpk + wpQKV[l] + 16384, 128, 128);
            k_pack<<<b128, 256, 0, stream>>>(v_w + (size_t)l * 16384, wpk + wpQKV[l] + 32768, 128, 128);
            k_pack<<<b128, 256, 0, stream>>>(o_w + (size_t)l * 16384, wpk + wpO[l], 128, 128);
            k_pack<<<b512, 256, 0, stream>>>(f1_w + (size_t)l * 65536, wpk + wpF1[l], 128, 512);
            k_pack<<<b512, 256, 0, stream>>>(f2_w + (size_t)l * 65536, wpk + wpF2[l], 512, 128);
            k_catb<<<1, 384, 0, stream>>>(q_b + l * 128, k_b + l * 128, v_b + l * 128, qkvB + l * 384);
        }
    }

    // ---- CSR build ----
    (void)hipMemsetAsync(cnt, 0, (size_t)NN * 4, stream);
    k_count<<<(NEDGE + 255) / 256, 256, 0, stream>>>(edst, cnt);
    k_scanA<<<NSB, 1024, 0, stream>>>(cnt, incl, btot);
    k_scanB<<<1, 64, 0, stream>>>(btot, boff);
    k_scanC<<<(NN + 255) / 256, 256, 0, stream>>>(cnt, incl, boff, rp);
    k_copyrp<<<(NN + 255) / 256, 256, 0, stream>>>(rp, cnt);
    k_scatter<<<(NEDGE + 255) / 256, 256, 0, stream>>>(esrc, edst, eval, cnt, ssrc, sval);

    // ---- propagation ----
    k_init<<<(NN * 32 + 255) / 256, 256, 0, stream>>>(drug, dis, nf);
    for (int s = 1; s <= NHOPS; s++)
        k_hopg<<<(NN * 32 + 255) / 256, 256, 0, stream>>>(nf, rp, ssrc, sval, s);

    // ---- per-node transformer + pooling, chunked; per-LAYER dispatch (L2-hot) ----
    for (int c = 0; c < nchunks; c++) {
        int cn0 = c * Nc;
        int cn = NN - cn0; if (cn > Nc) cn = Nc;
        if (cn <= 0) break;
        int Mc = cn * 8;
        int mb = (Mc + 15) / 16;
        int nb = (cn + 3) / 4;

        k_mgemm<0, 0, 0, 2><<<mb, 256, 0, stream>>>(nf + (size_t)cn0 * 1024, wpk + wpAtt,
                                                    att_b, hbuf, Mc, 128, 128);
        for (int l = 0; l < 2; l++) {
            k_layer<<<mb, 256, 0, stream>>>(hbuf, wpk + wpQKV[l], wpk + wpO[l],
                                            wpk + wpF1[l], wpk + wpF2[l],
                                            ln1_s + l * 128, ln1_b + l * 128,
                                            qkvB + l * 384, o_b + l * 128,
                                            ln2_s + l * 128, ln2_b + l * 128,
                                            f1_b + l * 512, f2_b + l * 128, Mc);
        }
        k_pool<<<nb, 256, 0, stream>>>(hbuf, fln_s, fln_b, aw, ab, out, cn, cn0);
    }
    (void)in_sizes; (void)n_in; (void)out_size;
}

// Round 32
// 2811.073 us; speedup vs baseline: 1.5828x; 1.0370x over previous
//
#include <hip/hip_runtime.h>
#include <hip/hip_bf16.h>

typedef __hip_bfloat16 bf16;
typedef __attribute__((ext_vector_type(8))) short s16x8;
typedef __attribute__((ext_vector_type(4))) float f32x4;

#define NDRUG 60000
#define NDIS  40000
#define NN    100000
#define DIM   128
#define NHOPS 7
#define NEDGE 800000
#define NSB   98

__device__ __forceinline__ float u2f(unsigned short u) {
    union { unsigned int i; float f; } c; c.i = ((unsigned int)u) << 16; return c.f;
}
__device__ __forceinline__ ushort f2u(float f) {
    bf16 h = __float2bfloat16(f);
    return *reinterpret_cast<ushort*>(&h);
}

// ---------------- propagation ----------------

__global__ void k_init(const float* __restrict__ drug, const float* __restrict__ dis,
                       ushort* __restrict__ nf) {
    int i = blockIdx.x * 256 + threadIdx.x;
    if (i >= NN * 32) return;
    int n = i >> 5, g = (i & 31) << 2;
    const float* sp = (n < NDRUG) ? drug + (size_t)n * 128 + g
                                  : dis + (size_t)(n - NDRUG) * 128 + g;
    float4 v = *(const float4*)sp;
    ushort4 o;
    o.x = f2u(v.x); o.y = f2u(v.y); o.z = f2u(v.z); o.w = f2u(v.w);
    *(ushort4*)(nf + (size_t)n * 1024 + g) = o;
}

__global__ void k_count(const int* __restrict__ edst, int* __restrict__ cnt) {
    int e = blockIdx.x * 256 + threadIdx.x;
    if (e < NEDGE) atomicAdd(&cnt[edst[e]], 1);
}

__global__ void k_scanA(const int* __restrict__ cnt, int* __restrict__ incl,
                        int* __restrict__ btot) {
    __shared__ int part[1024];
    int b = blockIdx.x, t = threadIdx.x;
    int i = b * 1024 + t;
    part[t] = (i < NN) ? cnt[i] : 0;
    __syncthreads();
    for (int o = 1; o < 1024; o <<= 1) {
        int u = (t >= o) ? part[t - o] : 0;
        __syncthreads();
        part[t] += u;
        __syncthreads();
    }
    if (i < NN) incl[i] = part[t];
    if (t == 1023) btot[b] = part[1023];
}

__global__ void k_scanB(const int* __restrict__ btot, int* __restrict__ boff) {
    if (threadIdx.x == 0) {
        int run = 0;
        for (int b = 0; b < NSB; b++) { boff[b] = run; run += btot[b]; }
        boff[NSB] = run;
    }
}

__global__ void k_scanC(const int* __restrict__ cnt, const int* __restrict__ incl,
                        const int* __restrict__ boff, int* __restrict__ rp) {
    int i = blockIdx.x * 256 + threadIdx.x;
    if (i < NN) rp[i] = incl[i] - cnt[i] + boff[i >> 10];
    if (i == 0) rp[NN] = boff[NSB];
}

__global__ void k_copyrp(const int* __restrict__ rp, int* __restrict__ cur) {
    int i = blockIdx.x * 256 + threadIdx.x;
    if (i < NN) cur[i] = rp[i];
}

__global__ void k_scatter(const int* __restrict__ esrc, const int* __restrict__ edst,
                          const float* __restrict__ eval, int* __restrict__ cur,
                          int* __restrict__ ssrc, float* __restrict__ sval) {
    int e = blockIdx.x * 256 + threadIdx.x;
    if (e >= NEDGE) return;
    int d = edst[e];
    int pos = atomicAdd(&cur[d], 1);
    ssrc[pos] = esrc[e];
    sval[pos] = eval[e];
}

__global__ void k_hopg(ushort* __restrict__ nf, const int* __restrict__ rp,
                       const int* __restrict__ ssrc, const float* __restrict__ sval, int s) {
    int t = blockIdx.x * 256 + threadIdx.x;
    if (t >= NN * 32) return;
    int n = t >> 5, d0 = (t & 31) << 2;
    int e0 = rp[n], e1 = rp[n + 1];
    float4 a = make_float4(0.f, 0.f, 0.f, 0.f);
    for (int e = e0; e < e1; e++) {
        int src = ssrc[e];
        float val = sval[e];
        ushort4 u = *(const ushort4*)(nf + (size_t)src * 1024 + (size_t)(s - 1) * 128 + d0);
        a.x += u2f(u.x) * val; a.y += u2f(u.y) * val;
        a.z += u2f(u.z) * val; a.w += u2f(u.w) * val;
    }
    ushort4 o;
    o.x = f2u(a.x); o.y = f2u(a.y); o.z = f2u(a.z); o.w = f2u(a.w);
    *(ushort4*)(nf + (size_t)n * 1024 + (size_t)s * 128 + d0) = o;
}

// ---------------- weight pre-pack ----------------

__global__ void k_pack(const float* __restrict__ W, ushort* __restrict__ P, int K, int Nout) {
    int idx = blockIdx.x * 256 + threadIdx.x;
    int tot = (Nout >> 4) * (K >> 3) * 16;
    if (idx >= tot) return;
    int c = idx & 15;
    int r = idx >> 4;
    int kb = r % (K >> 3);
    int nt = r / (K >> 3);
    ushort o[8];
    #pragma unroll
    for (int i = 0; i < 8; i++)
        o[i] = f2u(W[(size_t)(kb * 8 + i) * Nout + nt * 16 + c]);
    uint4 v;
    v.x = (uint)o[0] | ((uint)o[1] << 16);
    v.y = (uint)o[2] | ((uint)o[3] << 16);
    v.z = (uint)o[4] | ((uint)o[5] << 16);
    v.w = (uint)o[6] | ((uint)o[7] << 16);
    *(uint4*)(P + (size_t)idx * 8) = v;
}

__global__ void k_catb(const float* __restrict__ qb, const float* __restrict__ kb,
                       const float* __restrict__ vb, float* __restrict__ o) {
    int i = threadIdx.x;   // 384
    o[i] = (i < 128) ? qb[i] : ((i < 256) ? kb[i - 128] : vb[i - 256]);
}

// ---------------- MFMA bf16 GEMM, full-width blocks (R18-verified) ----------------

template <int ACT, int ADD, int OUTBF, int NTPW>
__global__ void k_mgemm(const ushort* __restrict__ X, const ushort* __restrict__ Wp,
                        const float* __restrict__ bias, void* __restrict__ Yv,
                        int M, int K, int Nout) {
    int w = threadIdx.x >> 6, lane = threadIdx.x & 63;
    int lr = lane & 15, lg = lane >> 4;
    int m0 = blockIdx.x * 16;
    int kb8 = K >> 3;
    int row = m0 + lr; if (row > M - 1) row = M - 1;
    const ushort* ap = X + (size_t)row * K + lg * 8;
    f32x4 acc[NTPW] = {};
    for (int k0 = 0; k0 < K; k0 += 32, ap += 32) {
        s16x8 af = *(const s16x8*)ap;
        int kb = (k0 >> 3) + lg;
        #pragma unroll
        for (int t = 0; t < NTPW; t++) {
            int nt = w + t * 4;
            const ushort* bp = Wp + (((size_t)nt * kb8 + kb) * 16 + lr) * 8;
            s16x8 bf_ = *(const s16x8*)bp;
            acc[t] = __builtin_amdgcn_mfma_f32_16x16x32_bf16(af, bf_, acc[t], 0, 0, 0);
        }
    }
    #pragma unroll
    for (int t = 0; t < NTPW; t++) {
        int n = (w + t * 4) * 16 + lr;
        float bv = bias[n];
        #pragma unroll
        for (int j = 0; j < 4; j++) {
            int m = m0 + lg * 4 + j;
            if (m >= M) continue;
            float v = acc[t][j] + bv;
            if (ACT == 1) {
                float x = v;
                float z = 0.7978845608028654f * (x + 0.044715f * x * x * x);
                v = x / (1.0f + __expf(-2.0f * z));
            }
            if (OUTBF) {
                ((ushort*)Yv)[(size_t)m * Nout + n] = f2u(v);
            } else if (ADD) {
                ((float*)Yv)[(size_t)m * Nout + n] += v;
            } else {
                ((float*)Yv)[(size_t)m * Nout + n] = v;
            }
        }
    }
}

// ---------------- fused FULL LAYER (R31 base) + MFMA attention ----------------
// 2 nodes (16 rows)/block; per-LAYER dispatch. Attention via MFMA:
// wave w = head w. QK^T: one 16x16x32 (A=q rows, B=k rows, K=32=dh); C holds
// all 16x16 dots, cross-node 8x8 blocks masked. Softmax per row over the
// node's 8-col block via shfl_xor(1,2,4) (never crosses the node bit).
// P (bf16, masked) -> psm LDS; PV = P @ V via 2x 16x16x32 (K zero-padded).

__global__ void k_layer(float* __restrict__ H,
                        const ushort* __restrict__ Wqkv, const ushort* __restrict__ Wo,
                        const ushort* __restrict__ Wf1, const ushort* __restrict__ Wf2,
                        const float* __restrict__ s1v, const float* __restrict__ b1v,
                        const float* __restrict__ bqkv, const float* __restrict__ bo,
                        const float* __restrict__ s2v, const float* __restrict__ b2v,
                        const float* __restrict__ bf1, const float* __restrict__ bf2,
                        int M) {
    __shared__ float  h[16][132];
    __shared__ ushort ylds[16][136];
    __shared__ ushort big[16][520];
    __shared__ ushort psm[4][16][16];
    int tid = threadIdx.x;
    int w = tid >> 6, lane = tid & 63;
    int lr = lane & 15, lg = lane >> 4;
    int m0 = blockIdx.x * 16;

    // load H tile -> h
    #pragma unroll
    for (int i = 0; i < 2; i++) {
        int gi = i * 256 + tid;
        int row = gi >> 5, c4 = (gi & 31) << 2;
        int grow = m0 + row; if (grow > M - 1) grow = M - 1;
        *(float4*)&h[row][c4] = *(const float4*)(H + (size_t)grow * 128 + c4);
    }
    __syncthreads();

    // LN1 (h -> ylds)
    #pragma unroll
    for (int i = 0; i < 4; i++) {
        int row = w * 4 + i;
        float2 x = *(const float2*)&h[row][lane * 2];
        float sum = x.x + x.y, sq = x.x * x.x + x.y * x.y;
        #pragma unroll
        for (int o = 32; o; o >>= 1) { sum += __shfl_xor(sum, o); sq += __shfl_xor(sq, o); }
        float mean = sum * (1.f / 128.f);
        float inv = rsqrtf(sq * (1.f / 128.f) - mean * mean + 1e-5f);
        float y0 = (x.x - mean) * inv * s1v[lane * 2 + 0] + b1v[lane * 2 + 0];
        float y1 = (x.y - mean) * inv * s1v[lane * 2 + 1] + b1v[lane * 2 + 1];
        *(uint*)&ylds[row][lane * 2] = (uint)f2u(y0) | ((uint)f2u(y1) << 16);
    }
    __syncthreads();

    // QKV GEMM (A from ylds) -> big
    {
        f32x4 acc[6] = {};
        for (int k0 = 0; k0 < 128; k0 += 32) {
            s16x8 af = *(const s16x8*)&ylds[lr][lg * 8 + k0];
            int kb = (k0 >> 3) + lg;
            #pragma unroll
            for (int t = 0; t < 6; t++) {
                int nt = w + t * 4;
                const ushort* bp = Wqkv + (((size_t)nt * 16 + kb) * 16 + lr) * 8;
                s16x8 bf_ = *(const s16x8*)bp;
                acc[t] = __builtin_amdgcn_mfma_f32_16x16x32_bf16(af, bf_, acc[t], 0, 0, 0);
            }
        }
        #pragma unroll
        for (int t = 0; t < 6; t++) {
            int n = (w + t * 4) * 16 + lr;
            float bv = bqkv[n];
            #pragma unroll
            for (int j = 0; j < 4; j++) big[lg * 4 + j][n] = f2u(acc[t][j] + bv);
        }
    }
    __syncthreads();

    // QK^T + softmax via MFMA (wave w = head w; rows/cols = node*8+idx)
    {
        f32x4 zero = {0.f, 0.f, 0.f, 0.f};
        s16x8 aq = *(const s16x8*)&big[lr][w * 32 + lg * 8];
        s16x8 bk = *(const s16x8*)&big[lr][128 + w * 32 + lg * 8];
        f32x4 c = __builtin_amdgcn_mfma_f32_16x16x32_bf16(aq, bk, zero, 0, 0, 0);
        const float scale = 0.17677669529663687f;
        #pragma unroll
        for (int j = 0; j < 4; j++) {
            float v = c[j] * scale;
            float mx = v;
            mx = fmaxf(mx, __shfl_xor(mx, 1));
            mx = fmaxf(mx, __shfl_xor(mx, 2));
            mx = fmaxf(mx, __shfl_xor(mx, 4));
            float e = __expf(v - mx);
            float sum = e;
            sum += __shfl_xor(sum, 1);
            sum += __shfl_xor(sum, 2);
            sum += __shfl_xor(sum, 4);
            int row = lg * 4 + j;
            bool valid = ((lr >> 3) == (row >> 3));
            psm[w][row][lr] = valid ? f2u(e / sum) : (ushort)0;
        }
    }
    // psm[w] written and read by the SAME wave -> no barrier needed

    // PV = P @ V via MFMA (K zero-padded to 32), writes ylds cols w*32..w*32+31
    {
        f32x4 zero = {0.f, 0.f, 0.f, 0.f};
        #pragma unroll
        for (int nh = 0; nh < 2; nh++) {
            s16x8 aP = {};
            s16x8 bV = {};
            if (lg < 2) {
                aP = *(const s16x8*)&psm[w][lr][lg * 8];
                #pragma unroll
                for (int i = 0; i < 8; i++)
                    bV[i] = (short)big[lg * 8 + i][256 + w * 32 + nh * 16 + lr];
            }
            f32x4 o = __builtin_amdgcn_mfma_f32_16x16x32_bf16(aP, bV, zero, 0, 0, 0);
            #pragma unroll
            for (int j = 0; j < 4; j++)
                ylds[lg * 4 + j][w * 32 + nh * 16 + lr] = f2u(o[j]);
        }
    }
    __syncthreads();

    // o-proj (A from ylds) += h
    {
        f32x4 acc[2] = {};
        for (int k0 = 0; k0 < 128; k0 += 32) {
            s16x8 af = *(const s16x8*)&ylds[lr][lg * 8 + k0];
            int kb = (k0 >> 3) + lg;
            #pragma unroll
            for (int t = 0; t < 2; t++) {
                int nt = w + t * 4;
                const ushort* bp = Wo + (((size_t)nt * 16 + kb) * 16 + lr) * 8;
                s16x8 bf_ = *(const s16x8*)bp;
                acc[t] = __builtin_amdgcn_mfma_f32_16x16x32_bf16(af, bf_, acc[t], 0, 0, 0);
            }
        }
        #pragma unroll
        for (int t = 0; t < 2; t++) {
            int n = (w + t * 4) * 16 + lr;
            float bv = bo[n];
            #pragma unroll
            for (int j = 0; j < 4; j++) h[lg * 4 + j][n] += acc[t][j] + bv;
        }
    }
    __syncthreads();

    // LN2 (h -> ylds)
    #pragma unroll
    for (int i = 0; i < 4; i++) {
        int row = w * 4 + i;
        float2 x = *(const float2*)&h[row][lane * 2];
        float sum = x.x + x.y, sq = x.x * x.x + x.y * x.y;
        #pragma unroll
        for (int o = 32; o; o >>= 1) { sum += __shfl_xor(sum, o); sq += __shfl_xor(sq, o); }
        float mean = sum * (1.f / 128.f);
        float inv = rsqrtf(sq * (1.f / 128.f) - mean * mean + 1e-5f);
        float y0 = (x.x - mean) * inv * s2v[lane * 2 + 0] + b2v[lane * 2 + 0];
        float y1 = (x.y - mean) * inv * s2v[lane * 2 + 1] + b2v[lane * 2 + 1];
        *(uint*)&ylds[row][lane * 2] = (uint)f2u(y0) | ((uint)f2u(y1) << 16);
    }
    __syncthreads();

    // f1 + gelu -> big
    {
        f32x4 acc[8] = {};
        for (int k0 = 0; k0 < 128; k0 += 32) {
            s16x8 af = *(const s16x8*)&ylds[lr][lg * 8 + k0];
            int kb = (k0 >> 3) + lg;
            #pragma unroll
            for (int t = 0; t < 8; t++) {
                int nt = w + t * 4;
                const ushort* bp = Wf1 + (((size_t)nt * 16 + kb) * 16 + lr) * 8;
                s16x8 bf_ = *(const s16x8*)bp;
                acc[t] = __builtin_amdgcn_mfma_f32_16x16x32_bf16(af, bf_, acc[t], 0, 0, 0);
            }
        }
        #pragma unroll
        for (int t = 0; t < 8; t++) {
            int n = (w + t * 4) * 16 + lr;
            float bv = bf1[n];
            #pragma unroll
            for (int j = 0; j < 4; j++) {
                float x = acc[t][j] + bv;
                float z = 0.7978845608028654f * (x + 0.044715f * x * x * x);
                big[lg * 4 + j][n] = f2u(x / (1.0f + __expf(-2.0f * z)));
            }
        }
    }
    __syncthreads();

    // f2 (K=512, A from big) += h
    {
        f32x4 acc[2] = {};
        for (int k0 = 0; k0 < 512; k0 += 32) {
            s16x8 af = *(const s16x8*)&big[lr][lg * 8 + k0];
            int kb = (k0 >> 3) + lg;
            #pragma unroll
            for (int t = 0; t < 2; t++) {
                int nt = w + t * 4;
                const ushort* bp = Wf2 + (((size_t)nt * 64 + kb) * 16 + lr) * 8;
                s16x8 bf_ = *(const s16x8*)bp;
                acc[t] = __builtin_amdgcn_mfma_f32_16x16x32_bf16(af, bf_, acc[t], 0, 0, 0);
            }
        }
        #pragma unroll
        for (int t = 0; t < 2; t++) {
            int n = (w + t * 4) * 16 + lr;
            float bv = bf2[n];
            #pragma unroll
            for (int j = 0; j < 4; j++) h[lg * 4 + j][n] += acc[t][j] + bv;
        }
    }
    __syncthreads();

    // store h -> H
    #pragma unroll
    for (int i = 0; i < 2; i++) {
        int gi = i * 256 + tid;
        int row = gi >> 5, c4 = (gi & 31) << 2;
        int grow = m0 + row;
        if (grow < M) *(float4*)(H + (size_t)grow * 128 + c4) = *(const float4*)&h[row][c4];
    }
}

// ---------------- final LN + hop-attention pooling ----------------

__global__ void k_pool(const float* __restrict__ Hc, const float* __restrict__ fs,
                       const float* __restrict__ fb, const float* __restrict__ aw,
                       const float* __restrict__ ab, float* __restrict__ out,
                       int Nc, int n0g) {
    int w = threadIdx.x >> 6, lane = threadIdx.x & 63;
    int nl = blockIdx.x * 4 + w;
    if (nl >= Nc) return;
    const float* hp = Hc + (size_t)nl * 1024;
    float s0 = fs[lane * 2], s1 = fs[lane * 2 + 1];
    float b0 = fb[lane * 2], b1 = fb[lane * 2 + 1];
    float2 yl[8];
    #pragma unroll
    for (int s = 0; s < 8; s++) {
        float2 x = *(const float2*)(hp + s * DIM + lane * 2);
        float sum = x.x + x.y, sq = x.x * x.x + x.y * x.y;
        #pragma unroll
        for (int o = 32; o; o >>= 1) { sum += __shfl_xor(sum, o); sq += __shfl_xor(sq, o); }
        float mean = sum * (1.f / 128.f);
        float inv = rsqrtf(sq * (1.f / 128.f) - mean * mean + 1e-5f);
        yl[s].x = (x.x - mean) * inv * s0 + b0;
        yl[s].y = (x.y - mean) * inv * s1 + b1;
    }
    float awn0 = aw[lane * 2], awn1 = aw[lane * 2 + 1];
    float awh0 = aw[128 + lane * 2], awh1 = aw[128 + lane * 2 + 1];
    float abv = ab[0];
    float lg[7];
    #pragma unroll
    for (int s = 0; s < 7; s++) {
        float part = yl[0].x * awn0 + yl[0].y * awn1 + yl[s + 1].x * awh0 + yl[s + 1].y * awh1;
        #pragma unroll
        for (int o = 32; o; o >>= 1) part += __shfl_xor(part, o);
        lg[s] = part + abv;
    }
    float mx = lg[0];
    #pragma unroll
    for (int s = 1; s < 7; s++) mx = fmaxf(mx, lg[s]);
    float sum = 0.f;
    #pragma unroll
    for (int s = 0; s < 7; s++) { lg[s] = __expf(lg[s] - mx); sum += lg[s]; }
    float rinv = 1.f / sum;
    float2 f = yl[0];
    #pragma unroll
    for (int s = 0; s < 7; s++) { f.x += lg[s] * rinv * yl[s + 1].x; f.y += lg[s] * rinv * yl[s + 1].y; }
    size_t ob = (size_t)(n0g + nl) * DIM + lane * 2;
    out[ob + 0] = f.x;
    out[ob + 1] = f.y;
}

// ---------------- host ----------------

extern "C" void kernel_launch(void* const* d_in, const int* in_sizes, int n_in,
                              void* d_out, int out_size, void* d_ws, size_t ws_size,
                              hipStream_t stream) {
    const float* drug  = (const float*)d_in[4];
    const float* dis   = (const float*)d_in[5];
    const int*   esrc  = (const int*)d_in[6];
    const int*   edst  = (const int*)d_in[7];
    const float* eval  = (const float*)d_in[8];
    const float* att_w = (const float*)d_in[9];
    const float* att_b = (const float*)d_in[10];
    const float* ln1_s = (const float*)d_in[11];
    const float* ln1_b = (const float*)d_in[12];
    const float* q_w   = (const float*)d_in[13];
    const float* q_b   = (const float*)d_in[14];
    const float* k_w   = (const float*)d_in[15];
    const float* k_b   = (const float*)d_in[16];
    const float* v_w   = (const float*)d_in[17];
    const float* v_b   = (const float*)d_in[18];
    const float* o_w   = (const float*)d_in[19];
    const float* o_b   = (const float*)d_in[20];
    const float* ln2_s = (const float*)d_in[21];
    const float* ln2_b = (const float*)d_in[22];
    const float* f1_w  = (const float*)d_in[23];
    const float* f1_b  = (const float*)d_in[24];
    const float* f2_w  = (const float*)d_in[25];
    const float* f2_b  = (const float*)d_in[26];
    const float* fln_s = (const float*)d_in[27];
    const float* fln_b = (const float*)d_in[28];
    const float* aw    = (const float*)d_in[29];
    const float* ab    = (const float*)d_in[30];
    float* out = (float*)d_out;

    char* ws = (char*)d_ws;
    size_t nfB = (size_t)NN * 1024 * 2;
    ushort* nf = (ushort*)ws;
    size_t off = (nfB + 255) & ~(size_t)255;

    ushort* wpk = (ushort*)(ws + off);
    size_t offCsr = off + (1 << 20);
    int*   rp   = (int*)(ws + offCsr);
    int*   cnt  = rp + (NN + 1);
    int*   ssrc = cnt + NN;
    float* sval = (float*)(ssrc + NEDGE);
    int*   incl = (int*)(sval + NEDGE);
    int*   btot = incl + NN;
    int*   boff = btot + 128;
    size_t csrInts = (size_t)(NN + 1) + NN + NEDGE + NEDGE + NN + 256;
    size_t off2 = offCsr + ((csrInts * 4 + 255) & ~(size_t)255);

    size_t scratchB = (ws_size > off2) ? ws_size - off2 : 0;
    long long ncMax = (long long)(scratchB / 4096);
    ncMax &= ~1LL;
    if (ncMax < 2) ncMax = 2;
    int Nc = (int)((ncMax < NN) ? ncMax : NN);
    int nchunks = (NN + Nc - 1) / Nc;
    Nc = (NN + nchunks - 1) / nchunks;
    if (Nc & 1) Nc++;
    float* hbuf = (float*)(ws + off2);

    size_t wpAtt = 0;
    size_t wpQKV[2], wpO[2], wpF1[2], wpF2[2];
    {
        size_t p = 16384;
        for (int l = 0; l < 2; l++) {
            wpQKV[l] = p; p += 49152;
            wpO[l]   = p; p += 16384;
            wpF1[l]  = p; p += 65536;
            wpF2[l]  = p; p += 65536;
        }
    }
    float* qkvB = (float*)(wpk + 409600);

    // ---- pack weights ----
    {
        int b128 = (16384 / 8 + 255) / 256;
        int b512 = (65536 / 8 + 255) / 256;
        k_pack<<<b128, 256, 0, stream>>>(att_w, wpk + wpAtt, 128, 128);
        for (int l = 0; l < 2; l++) {
            k_pack<<<b128, 256, 0, stream>>>(q_w + (size_t)l * 16384, wpk + wpQKV[l], 128, 128);
            k_pack<<<b128, 256, 0, stream>>>(k_w + (size_t)l * 16384, wpk + wpQKV[l] + 16384, 128, 128);
            k_pack<<<b128, 256, 0, stream>>>(v_w + (size_t)l * 16384, wpk + wpQKV[l] + 32768, 128, 128);
            k_pack<<<b128, 256, 0, stream>>>(o_w + (size_t)l * 16384, wpk + wpO[l], 128, 128);
            k_pack<<<b512, 256, 0, stream>>>(f1_w + (size_t)l * 65536, wpk + wpF1[l], 128, 512);
            k_pack<<<b512, 256, 0, stream>>>(f2_w + (size_t)l * 65536, wpk + wpF2[l], 512, 128);
            k_catb<<<1, 384, 0, stream>>>(q_b + l * 128, k_b + l * 128, v_b + l * 128, qkvB + l * 384);
        }
    }

    // ---- CSR build ----
    (void)hipMemsetAsync(cnt, 0, (size_t)NN * 4, stream);
    k_count<<<(NEDGE + 255) / 256, 256, 0, stream>>>(edst, cnt);
    k_scanA<<<NSB, 1024, 0, stream>>>(cnt, incl, btot);
    k_scanB<<<1, 64, 0, stream>>>(btot, boff);
    k_scanC<<<(NN + 255) / 256, 256, 0, stream>>>(cnt, incl, boff, rp);
    k_copyrp<<<(NN + 255) / 256, 256, 0, stream>>>(rp, cnt);
    k_scatter<<<(NEDGE + 255) / 256, 256, 0, stream>>>(esrc, edst, eval, cnt, ssrc, sval);

    // ---- propagation ----
    k_init<<<(NN * 32 + 255) / 256, 256, 0, stream>>>(drug, dis, nf);
    for (int s = 1; s <= NHOPS; s++)
        k_hopg<<<(NN * 32 + 255) / 256, 256, 0, stream>>>(nf, rp, ssrc, sval, s);

    // ---- per-node transformer + pooling, chunked; per-LAYER dispatch (L2-hot) ----
    for (int c = 0; c < nchunks; c++) {
        int cn0 = c * Nc;
        int cn = NN - cn0; if (cn > Nc) cn = Nc;
        if (cn <= 0) break;
        int Mc = cn * 8;
        int mb = (Mc + 15) / 16;
        int nb = (cn + 3) / 4;

        k_mgemm<0, 0, 0, 2><<<mb, 256, 0, stream>>>(nf + (size_t)cn0 * 1024, wpk + wpAtt,
                                                    att_b, hbuf, Mc, 128, 128);
        for (int l = 0; l < 2; l++) {
            k_layer<<<mb, 256, 0, stream>>>(hbuf, wpk + wpQKV[l], wpk + wpO[l],
                                            wpk + wpF1[l], wpk + wpF2[l],
                                            ln1_s + l * 128, ln1_b + l * 128,
                                            qkvB + l * 384, o_b + l * 128,
                                            ln2_s + l * 128, ln2_b + l * 128,
                                            f1_b + l * 512, f2_b + l * 128, Mc);
        }
        k_pool<<<nb, 256, 0, stream>>>(hbuf, fln_s, fln_b, aw, ab, out, cn, cn0);
    }
    (void)in_sizes; (void)n_in; (void)out_size;
}